// Round 12
// baseline (287.534 us; speedup 1.0000x reference)
//
#include <hip/hip_runtime.h>
#include <stdint.h>

#define NCELL (512 * 512)
#define DIN   136

// output layout (flat f32, concat in return order)
#define OUT_LAT 2097152ull                 // N*8
#define OUT_C   35651584ull                // OUT_LAT + N*128
#define OUT_H   52428800ull                // OUT_C + N*64

// packed-weight offsets in d_ws (bf16 elements)
#define WPRE_OFF  0        // [5][64][32]   = 10240
#define W2_OFF    10240    // [4][256][32]  = 32768
#define WPOST_OFF 43008    // [2][160][32]  = 10240 ; n' 0..7 dyn, 8..31 pad, 32..159 lat
#define WTOTAL    53248

#define ROWB 336           // Xs bytes per cell-row
#define MROW 32            // cells per block (halved: 8 blocks/CU at same footprint)

typedef __bf16 bf16x8 __attribute__((ext_vector_type(8)));
typedef __bf16 bf16x2 __attribute__((ext_vector_type(2)));
typedef float  f32x4  __attribute__((ext_vector_type(4)));

// Native casts -> compiler emits v_cvt_pk_bf16_f32 (RTNE)
__device__ __forceinline__ unsigned short f2bf(float f) {
    __bf16 v = (__bf16)f;
    unsigned short r;
    __builtin_memcpy(&r, &v, 2);
    return r;
}
__device__ __forceinline__ int pack2(float a, float b) {
    bf16x2 v{(__bf16)a, (__bf16)b};
    int r;
    __builtin_memcpy(&r, &v, 4);
    return r;
}
__device__ __forceinline__ float fast_sigmoid(float x) {
    return __builtin_amdgcn_rcpf(1.f + __expf(-x));
}
__device__ __forceinline__ float fast_tanh(float x) {
    float e = __expf(2.f * x);              // inf-safe: rcp(inf)=0 -> 1; e->0 -> -1
    return 1.f - 2.f * __builtin_amdgcn_rcpf(e + 1.f);
}
__device__ __forceinline__ float bf2f_lo(int u) {
    return __uint_as_float((unsigned)u << 16);
}
__device__ __forceinline__ float bf2f_hi(int u) {
    return __uint_as_float((unsigned)u & 0xffff0000u);
}

// Repack weights to bf16, MFMA-B-fragment-friendly: [K/32][Ncol][32]
__global__ void prep_weights(const float* __restrict__ Wpre,
                             const float* __restrict__ Wih,
                             const float* __restrict__ Whh,
                             const float* __restrict__ Wpost,
                             unsigned short* __restrict__ ws) {
    int i = blockIdx.x * 256 + threadIdx.x;
    if (i < 10240) {                                   // Wpre' : K 136->160 pad, N=64
        int k = i & 31, n = (i >> 5) & 63, s = i >> 11;
        int K = s * 32 + k;
        ws[i] = (K < DIN) ? f2bf(Wpre[K * 64 + n]) : (unsigned short)0;
    } else if (i < 43008) {                            // W2'   : K=128 (ih||hh), N=256
        int j = i - 10240;
        int k = j & 31, n = (j >> 5) & 255, s = j >> 13;
        int K = s * 32 + k;
        float v = (K < 64) ? Wih[K * 256 + n] : Whh[(K - 64) * 256 + n];
        ws[i] = f2bf(v);
    } else if (i < WTOTAL) {                           // Wpost2: [2][160][32], line-aligned
        int j = i - 43008;
        int k = j & 31;
        int t2 = j >> 5;            // 0..319
        int n = t2 % 160;
        int s = t2 / 160;
        int K = s * 32 + k;         // 0..63
        float v = 0.f;
        if (n < 8)        v = Wpost[K * DIN + n];          // dyn cols
        else if (n >= 32) v = Wpost[K * DIN + (n - 24)];   // lat cols 0..127
        ws[i] = f2bf(v);
    }
}

// Cooperative fused kernel: block = 256 threads (4 waves) = 32 cells.
// 8 blocks/CU (LDS 18.9KB, VGPR<=64) = 32 waves/CU at the SAME cells-in-flight
// footprint as the proven 4x64 schedule (2048 resident blocks x 32 cells = 64K
// cell window). Two-pass GEMM2 keeps acc pressure at 16.
__global__ __launch_bounds__(256, 8) void knet_fused(
    const float* __restrict__ dyn_in,
    const float* __restrict__ lat_prev,
    const float* __restrict__ lstm_c,
    const float* __restrict__ lstm_h,
    const unsigned short* __restrict__ wsp,
    const float* __restrict__ b_pre,
    const float* __restrict__ b_lstm,
    const float* __restrict__ b_post,
    float* __restrict__ out) {
    // Xs: X bf16 cols 0..159 during GEMM1 (bytes 272..319 zero pad).
    //     After GEMM1 sync (Xs dead): hn -> bytes 0..127 (XOR swz), cn -> 128..255.
    __shared__ __align__(16) char Xs[MROW * ROWB];
    // A2s: [32][128] bf16 (cols 0..63 = pre, 64..127 = h_prev), XOR-swizzled rows
    __shared__ __align__(16) unsigned short A2s[MROW * 128];

    const int t  = threadIdx.x;
    const int p0 = blockIdx.x * MROW;
    const unsigned short* wpre_p  = wsp + WPRE_OFF;
    const unsigned short* w2_p    = wsp + W2_OFF;
    const unsigned short* wpost_p = wsp + WPOST_OFF;

    // ---------------- phase 0: staging (analytic topology) ----------------
    {
        // h_prev -> A2s cols 64..127 (bf16, swizzled). 8 values/thread.
        int r = t >> 3, q = t & 7;
        int sw = (r & 7) << 4;
        const float4* hp = (const float4*)(lstm_h + (size_t)(p0 + r) * 64 + q * 8);
        float4 v0 = hp[0], v1 = hp[1];
        int4 w0{pack2(v0.x, v0.y), pack2(v0.z, v0.w),
                pack2(v1.x, v1.y), pack2(v1.z, v1.w)};
        *(int4*)((char*)A2s + r * 256 + ((128 + 16 * q) ^ sw)) = w0;
        // zero pad X cols 136..159 (bytes 272..319)
        if (q < 3) *(int4*)(Xs + r * ROWB + 272 + 16 * q) = int4{0, 0, 0, 0};
    }
    if (t < 128) {  // dyn_in -> X cols 0..7 (2 floats/thread)
        int r = t >> 2, c = (t & 3) * 2;
        float2 v = *(const float2*)(dyn_in + (size_t)(p0 + r) * 8 + c);
        *(int*)(Xs + r * ROWB + c * 2) = pack2(v.x, v.y);
    }
    {   // lat gather -> X cols 8..135 ; analytic topology, 1 (row,dir)/thread
        const int gr = t >> 3, gd = t & 7;
        // offsets {(-1,-1),(-1,0),(-1,1),(0,-1),(0,1),(1,-1),(1,0),(1,1)}
        const int dr = (gd < 3) ? -1 : ((gd < 5) ? 0 : 1);
        const int dc = (gd < 3) ? (gd - 1)
                                : ((gd < 5) ? ((gd == 3) ? -1 : 1) : (gd - 6));
        const int nr = (p0 >> 9) + dr;        // all 32 cells share one grid row
        int nc = (p0 & 511) + gr + dc;
        int src;
        if (nr == -1)       src = (nc + 256) & 511;
        else if (nr == 512) src = (511 << 9) | ((nc + 256) & 511);
        else                src = (nr << 9) | ((nc + 512) & 511);
        const float4* lp = (const float4*)(lat_prev + (size_t)src * 128 + gd * 16);
        float4 a0 = lp[0], a1 = lp[1], a2 = lp[2], a3 = lp[3];
        char* dst = Xs + gr * ROWB + 16 + 32 * gd;
        *(int4*)dst = int4{pack2(a0.x, a0.y), pack2(a0.z, a0.w),
                           pack2(a1.x, a1.y), pack2(a1.z, a1.w)};
        *(int4*)(dst + 16) = int4{pack2(a2.x, a2.y), pack2(a2.z, a2.w),
                                  pack2(a3.x, a3.y), pack2(a3.z, a3.w)};
    }
    __syncthreads();

    const int lane = t & 63;
    const int w    = t >> 6;     // wave id = N-tile owner
    const int lr   = lane & 15;
    const int lg   = lane >> 4;
    const int hid  = w * 16 + lr;

    // ---------------- GEMM1: X[32x160] @ Wpre'[160x64] -> pre -> A2s cols 0..63
    {
        f32x4 acc1[2];
#pragma unroll
        for (int m = 0; m < 2; ++m) acc1[m] = (f32x4){0.f, 0.f, 0.f, 0.f};
#pragma unroll
        for (int s = 0; s < 5; ++s) {
            bf16x8 b = *(const bf16x8*)(wpre_p + ((s * 64 + hid) * 32 + lg * 8));
#pragma unroll
            for (int m = 0; m < 2; ++m) {
                bf16x8 a = *(const bf16x8*)(Xs + (m * 16 + lr) * ROWB + s * 64 + lg * 16);
                acc1[m] = __builtin_amdgcn_mfma_f32_16x16x32_bf16(a, b, acc1[m], 0, 0, 0);
            }
        }
        float bp = b_pre[hid];
        int colb = hid * 2;
#pragma unroll
        for (int m = 0; m < 2; ++m)
#pragma unroll
            for (int rr = 0; rr < 4; ++rr) {
                int row = m * 16 + lg * 4 + rr;
                float pv = fast_tanh(acc1[m][rr] + bp);
                *(unsigned short*)((char*)A2s + row * 256 + (colb ^ ((row & 7) << 4))) =
                    f2bf(pv);
            }
    }
    __syncthreads();   // pre/h visible; all GEMM1 Xs reads retired (Xs dead)

    // ---------------- GEMM2: [pre||h][32x128] @ W2'[128x256], 2 passes + LSTM ------
    {
        const float bi  = b_lstm[hid],       bg = b_lstm[128 + hid];
        const float bf_ = b_lstm[64 + hid],  bo = b_lstm[192 + hid];

        // ---- pass A: i (tile w), g (tile w+8) ----
        f32x4 acc[2][2];
#pragma unroll
        for (int m = 0; m < 2; ++m)
#pragma unroll
            for (int j = 0; j < 2; ++j) acc[m][j] = (f32x4){0.f, 0.f, 0.f, 0.f};
#pragma unroll
        for (int s = 0; s < 4; ++s) {
            bf16x8 b0 = *(const bf16x8*)(w2_p + ((s * 256 + (w)     * 16 + lr) * 32 + lg * 8));
            bf16x8 b1 = *(const bf16x8*)(w2_p + ((s * 256 + (w + 8) * 16 + lr) * 32 + lg * 8));
#pragma unroll
            for (int m = 0; m < 2; ++m) {
                int row = m * 16 + lr;
                int cb  = (s * 32 + lg * 8) * 2;
                bf16x8 a = *(const bf16x8*)((char*)A2s + row * 256 +
                                            (cb ^ ((row & 7) << 4)));
                acc[m][0] = __builtin_amdgcn_mfma_f32_16x16x32_bf16(a, b0, acc[m][0], 0, 0, 0);
                acc[m][1] = __builtin_amdgcn_mfma_f32_16x16x32_bf16(a, b1, acc[m][1], 0, 0, 0);
            }
        }
        // ig = sigmoid(i)*tanh(g), packed bf16 (4 regs)
        int igp[4];
#pragma unroll
        for (int m = 0; m < 2; ++m)
#pragma unroll
            for (int pp = 0; pp < 2; ++pp) {
                float g0 = fast_sigmoid(acc[m][0][2 * pp]     + bi) *
                           fast_tanh(acc[m][1][2 * pp]     + bg);
                float g1 = fast_sigmoid(acc[m][0][2 * pp + 1] + bi) *
                           fast_tanh(acc[m][1][2 * pp + 1] + bg);
                igp[m * 2 + pp] = pack2(g0, g1);
            }

        // prefetch c_old (hidden under pass B MFMAs)
        float cpf[8];
#pragma unroll
        for (int m = 0; m < 2; ++m)
#pragma unroll
            for (int rr = 0; rr < 4; ++rr)
                cpf[m * 4 + rr] =
                    lstm_c[(size_t)(p0 + m * 16 + lg * 4 + rr) * 64 + hid];

        // ---- pass B: f (tile w+4), o (tile w+12) ----
#pragma unroll
        for (int m = 0; m < 2; ++m)
#pragma unroll
            for (int j = 0; j < 2; ++j) acc[m][j] = (f32x4){0.f, 0.f, 0.f, 0.f};
#pragma unroll
        for (int s = 0; s < 4; ++s) {
            bf16x8 b0 = *(const bf16x8*)(w2_p + ((s * 256 + (w + 4)  * 16 + lr) * 32 + lg * 8));
            bf16x8 b1 = *(const bf16x8*)(w2_p + ((s * 256 + (w + 12) * 16 + lr) * 32 + lg * 8));
#pragma unroll
            for (int m = 0; m < 2; ++m) {
                int row = m * 16 + lr;
                int cb  = (s * 32 + lg * 8) * 2;
                bf16x8 a = *(const bf16x8*)((char*)A2s + row * 256 +
                                            (cb ^ ((row & 7) << 4)));
                acc[m][0] = __builtin_amdgcn_mfma_f32_16x16x32_bf16(a, b0, acc[m][0], 0, 0, 0);
                acc[m][1] = __builtin_amdgcn_mfma_f32_16x16x32_bf16(a, b1, acc[m][1], 0, 0, 0);
            }
        }
        // ---- LSTM pointwise: hn -> Xs[0..127], cn -> Xs[128..255] (swizzled) ----
#pragma unroll
        for (int m = 0; m < 2; ++m)
#pragma unroll
            for (int rr = 0; rr < 4; ++rr) {
                int row = m * 16 + lg * 4 + rr;
                float fv = fast_sigmoid(acc[m][0][rr] + bf_);
                float ov = fast_sigmoid(acc[m][1][rr] + bo);
                float igv = (rr & 1) ? bf2f_hi(igp[m * 2 + (rr >> 1)])
                                     : bf2f_lo(igp[m * 2 + (rr >> 1)]);
                float cn = fv * cpf[m * 4 + rr] + igv;
                float hn = ov * fast_tanh(cn);
                int sw = (row & 7) << 4;
                char* rp = Xs + row * ROWB;
                *(unsigned short*)(rp + ((2 * hid) ^ sw))       = f2bf(hn);
                *(unsigned short*)(rp + 128 + ((2 * hid) ^ sw)) = f2bf(cn);
            }
    }
    __syncthreads();   // hn/cn visible

    // ---------------- cooperative full-line c/h stores ----------------
    {
        int row = t >> 3;
        int ch  = t & 7;
        const char* rp = Xs + row * ROWB;
        int off = (ch * 16) ^ ((row & 7) << 4);
        int4 hv = *(const int4*)(rp + off);
        int4 cv = *(const int4*)(rp + 128 + off);
        size_t rb = (size_t)(p0 + row) * 64 + ch * 8;
        float4 a0{bf2f_lo(cv.x), bf2f_hi(cv.x), bf2f_lo(cv.y), bf2f_hi(cv.y)};
        float4 a1{bf2f_lo(cv.z), bf2f_hi(cv.z), bf2f_lo(cv.w), bf2f_hi(cv.w)};
        *(float4*)(out + OUT_C + rb)     = a0;
        *(float4*)(out + OUT_C + rb + 4) = a1;
        float4 b0{bf2f_lo(hv.x), bf2f_hi(hv.x), bf2f_lo(hv.y), bf2f_hi(hv.y)};
        float4 b1{bf2f_lo(hv.z), bf2f_hi(hv.z), bf2f_lo(hv.w), bf2f_hi(hv.w)};
        *(float4*)(out + OUT_H + rb)     = b0;
        *(float4*)(out + OUT_H + rb + 4) = b1;
    }

    // ---------------- GEMM3: hn[32x64] @ Wpost2'[64x160], tanh -> dyn/lat ----------
    // wave w owns lat tiles {2w+2, 2w+3} = lat 32-col line w (single-writer lines);
    // wave 0 additionally does the dyn tile.
    {
        f32x4 acc3[2][3];
#pragma unroll
        for (int m = 0; m < 2; ++m)
#pragma unroll
            for (int jj = 0; jj < 3; ++jj) acc3[m][jj] = (f32x4){0.f, 0.f, 0.f, 0.f};
#pragma unroll
        for (int s = 0; s < 2; ++s) {
            bf16x8 a[2];
#pragma unroll
            for (int m = 0; m < 2; ++m) {
                int row = m * 16 + lr;
                a[m] = *(const bf16x8*)(Xs + row * ROWB +
                                        ((s * 64 + lg * 16) ^ ((lr & 7) << 4)));
            }
#pragma unroll
            for (int jj = 0; jj < 3; ++jj) {
                if (jj == 0 && w != 0) continue;
                int n = (jj == 0) ? 0 : (2 * w + 1 + jj);
                bf16x8 b =
                    *(const bf16x8*)(wpost_p + ((s * 160 + n * 16 + lr) * 32 + lg * 8));
#pragma unroll
                for (int m = 0; m < 2; ++m)
                    acc3[m][jj] = __builtin_amdgcn_mfma_f32_16x16x32_bf16(a[m], b,
                                                                          acc3[m][jj],
                                                                          0, 0, 0);
            }
        }
        if (w == 0 && lr < 8) {                       // dyn tile
            float bpv = b_post[lr];
#pragma unroll
            for (int m = 0; m < 2; ++m)
#pragma unroll
                for (int rr = 0; rr < 4; ++rr) {
                    int row = m * 16 + lg * 4 + rr;
                    out[(size_t)(p0 + row) * 8 + lr] =
                        fast_tanh(acc3[m][0][rr] + bpv);
                }
        }
#pragma unroll
        for (int jj = 1; jj < 3; ++jj) {              // lat tiles (line w)
            int n = 2 * w + 1 + jj;
            int L = n * 16 + lr - 32;                 // lat col 0..127
            float bpv = b_post[L + 8];
#pragma unroll
            for (int m = 0; m < 2; ++m)
#pragma unroll
                for (int rr = 0; rr < 4; ++rr) {
                    int row = m * 16 + lg * 4 + rr;
                    out[OUT_LAT + (size_t)(p0 + row) * 128 + L] =
                        fast_tanh(acc3[m][jj][rr] + bpv);
                }
        }
    }
}

extern "C" void kernel_launch(void* const* d_in, const int* in_sizes, int n_in,
                              void* d_out, int out_size, void* d_ws, size_t ws_size,
                              hipStream_t stream) {
    const float* dyn_in   = (const float*)d_in[0];
    const float* lat_prev = (const float*)d_in[1];
    const float* lstm_c   = (const float*)d_in[2];
    const float* lstm_h   = (const float*)d_in[3];
    const float* W_pre  = (const float*)d_in[7];
    const float* b_pre  = (const float*)d_in[8];
    const float* W_ih   = (const float*)d_in[9];
    const float* W_hh   = (const float*)d_in[10];
    const float* b_lstm = (const float*)d_in[11];
    const float* W_post = (const float*)d_in[12];
    const float* b_post = (const float*)d_in[13];
    unsigned short* wsp = (unsigned short*)d_ws;

    prep_weights<<<(WTOTAL + 255) / 256, 256, 0, stream>>>(W_pre, W_ih, W_hh, W_post, wsp);
    knet_fused<<<NCELL / MROW, 256, 0, stream>>>(dyn_in, lat_prev, lstm_c, lstm_h,
                                                 wsp, b_pre, b_lstm, b_post, (float*)d_out);
}

// Round 14
// 186.717 us; speedup vs baseline: 1.5399x; 1.5399x over previous
//
#include <hip/hip_runtime.h>
#include <stdint.h>

#define NCELL (512 * 512)
#define DIN   136

// output layout (flat f32, concat in return order)
#define OUT_LAT 2097152ull                 // N*8
#define OUT_C   35651584ull                // OUT_LAT + N*128
#define OUT_H   52428800ull                // OUT_C + N*64

// packed-weight offsets in d_ws (bf16 elements)
#define WPRE_OFF  0        // [5][64][32]   = 10240
#define W2_OFF    10240    // [4][256][32]  = 32768
#define WPOST_OFF 43008    // [2][160][32]  = 10240 ; n' 0..7 dyn, 8..31 pad, 32..159 lat
#define WTOTAL    53248

#define ROWB 336           // Xs bytes per cell-row

typedef __bf16 bf16x8 __attribute__((ext_vector_type(8)));
typedef __bf16 bf16x2 __attribute__((ext_vector_type(2)));
typedef float  f32x4  __attribute__((ext_vector_type(4)));

// Native casts -> compiler emits v_cvt_pk_bf16_f32 (RTNE)
__device__ __forceinline__ unsigned short f2bf(float f) {
    __bf16 v = (__bf16)f;
    unsigned short r;
    __builtin_memcpy(&r, &v, 2);
    return r;
}
__device__ __forceinline__ int pack2(float a, float b) {
    bf16x2 v{(__bf16)a, (__bf16)b};
    int r;
    __builtin_memcpy(&r, &v, 4);
    return r;
}
__device__ __forceinline__ float fast_sigmoid(float x) {
    return __builtin_amdgcn_rcpf(1.f + __expf(-x));
}
__device__ __forceinline__ float fast_tanh(float x) {
    float e = __expf(2.f * x);              // inf-safe: rcp(inf)=0 -> 1; e->0 -> -1
    return 1.f - 2.f * __builtin_amdgcn_rcpf(e + 1.f);
}
__device__ __forceinline__ float bf2f_lo(int u) {
    return __uint_as_float((unsigned)u << 16);
}
__device__ __forceinline__ float bf2f_hi(int u) {
    return __uint_as_float((unsigned)u & 0xffff0000u);
}

// Repack weights to bf16, MFMA-B-fragment-friendly: [K/32][Ncol][32]
__global__ void prep_weights(const float* __restrict__ Wpre,
                             const float* __restrict__ Wih,
                             const float* __restrict__ Whh,
                             const float* __restrict__ Wpost,
                             unsigned short* __restrict__ ws) {
    int i = blockIdx.x * 256 + threadIdx.x;
    if (i < 10240) {                                   // Wpre' : K 136->160 pad, N=64
        int k = i & 31, n = (i >> 5) & 63, s = i >> 11;
        int K = s * 32 + k;
        ws[i] = (K < DIN) ? f2bf(Wpre[K * 64 + n]) : (unsigned short)0;
    } else if (i < 43008) {                            // W2'   : K=128 (ih||hh), N=256
        int j = i - 10240;
        int k = j & 31, n = (j >> 5) & 255, s = j >> 13;
        int K = s * 32 + k;
        float v = (K < 64) ? Wih[K * 256 + n] : Whh[(K - 64) * 256 + n];
        ws[i] = f2bf(v);
    } else if (i < WTOTAL) {                           // Wpost2: [2][160][32], line-aligned
        int j = i - 43008;
        int k = j & 31;
        int t2 = j >> 5;            // 0..319
        int n = t2 % 160;
        int s = t2 / 160;
        int K = s * 32 + k;         // 0..63
        float v = 0.f;
        if (n < 8)        v = Wpost[K * DIN + n];          // dyn cols
        else if (n >= 32) v = Wpost[K * DIN + (n - 24)];   // lat cols 0..127
        ws[i] = f2bf(v);
    }
}

// Cooperative fused kernel: block = 256 threads (4 waves) = 64 cells.
// R7 structure (proven: 4096 blocks, 4/CU, two-buffer race-free layout) with:
//  - XCD-chunked block swizzle: XCD k owns contiguous cell range [k*32768, ...)
//    so row-neighbor blocks (which share gather lines) hit the SAME L2.
//  - analytic gather topology (no coming_from stream, no dependent index load)
//  - non-temporal c/h stores (streaming writes no longer evict the lat_prev
//    read window out of the 4MB per-XCD L2).
__global__ __launch_bounds__(256, 4) void knet_fused(
    const float* __restrict__ dyn_in,
    const float* __restrict__ lat_prev,
    const float* __restrict__ lstm_c,
    const float* __restrict__ lstm_h,
    const unsigned short* __restrict__ wsp,
    const float* __restrict__ b_pre,
    const float* __restrict__ b_lstm,
    const float* __restrict__ b_post,
    float* __restrict__ out) {
    // Xs: X bf16 cols 0..159 during GEMM1 (bytes 272..319 zero pad).
    //     During LSTM epilogue (Xs dead): hn -> bytes 0..127 (XOR swz),
    //     cn -> bytes 128..255 (same swz). Read by GEMM3 + coop stores.
    __shared__ __align__(16) char Xs[64 * ROWB];
    // A2s: [64][128] bf16 (cols 0-63 = pre, 64-127 = h_prev), XOR-swizzled rows
    __shared__ __align__(16) unsigned short A2s[64 * 128];

    const int t   = threadIdx.x;
    // XCD-chunked swizzle: dispatch round-robins bid%8 across XCDs; remap so
    // XCD k gets the contiguous block range [k*512, (k+1)*512).
    const int bid = blockIdx.x;
    const int p0  = ((bid & 7) * 512 + (bid >> 3)) * 64;
    const unsigned short* wpre_p  = wsp + WPRE_OFF;
    const unsigned short* w2_p    = wsp + W2_OFF;
    const unsigned short* wpost_p = wsp + WPOST_OFF;

    // ---------------- phase 0: staging ----------------
    {
        // h_prev -> A2s cols 64..127 (bf16, swizzled). 16 values/thread.
        int r = t >> 2, q = t & 3;
        int sw = (r & 7) << 4;
        const float4* hp = (const float4*)(lstm_h + (size_t)(p0 + r) * 64 + q * 16);
        float4 v0 = hp[0], v1 = hp[1], v2 = hp[2], v3 = hp[3];
        char* rowp = (char*)A2s + r * 256;
        int4 w0{pack2(v0.x, v0.y), pack2(v0.z, v0.w), pack2(v1.x, v1.y), pack2(v1.z, v1.w)};
        int4 w1{pack2(v2.x, v2.y), pack2(v2.z, v2.w), pack2(v3.x, v3.y), pack2(v3.z, v3.w)};
        *(int4*)(rowp + ((128 + 32 * q) ^ sw))      = w0;
        *(int4*)(rowp + ((128 + 32 * q + 16) ^ sw)) = w1;

        // zero pad X cols 136..159 (bytes 272..319)
        if (q < 3) *(int4*)(Xs + r * ROWB + 272 + 16 * q) = int4{0, 0, 0, 0};
    }
    if (t < 128) {  // dyn_in -> X cols 0..7
        int r = t >> 1, c = (t & 1) * 4;
        float4 v = *(const float4*)(dyn_in + (size_t)(p0 + r) * 8 + c);
        int2 wv{pack2(v.x, v.y), pack2(v.z, v.w)};
        *(int2*)(Xs + r * ROWB + c * 2) = wv;
    }
    {   // lat gather -> X cols 8..135 ; analytic topology (= _build_topology)
        const int gra = t >> 3, grb = gra + 32, gd = t & 7;
        // offsets {(-1,-1),(-1,0),(-1,1),(0,-1),(0,1),(1,-1),(1,0),(1,1)}
        const int dr = (gd < 3) ? -1 : ((gd < 5) ? 0 : 1);
        const int dc = (gd < 3) ? (gd - 1)
                                : ((gd < 5) ? ((gd == 3) ? -1 : 1) : (gd - 6));
        const int nr = (p0 >> 9) + dr;        // all 64 cells share one grid row
        const int colbase = p0 & 511;
        int nc_a = colbase + gra + dc;
        int nc_b = colbase + grb + dc;
        int src_a, src_b;
        if (nr == -1) {
            src_a = (nc_a + 256) & 511;
            src_b = (nc_b + 256) & 511;
        } else if (nr == 512) {
            src_a = (511 << 9) | ((nc_a + 256) & 511);
            src_b = (511 << 9) | ((nc_b + 256) & 511);
        } else {
            src_a = (nr << 9) | ((nc_a + 512) & 511);
            src_b = (nr << 9) | ((nc_b + 512) & 511);
        }
        const float4* lpA = (const float4*)(lat_prev + (size_t)src_a * 128 + gd * 16);
        float4 a0 = lpA[0], a1 = lpA[1], a2 = lpA[2], a3 = lpA[3];
        const float4* lpB = (const float4*)(lat_prev + (size_t)src_b * 128 + gd * 16);
        float4 b0 = lpB[0], b1 = lpB[1], b2 = lpB[2], b3 = lpB[3];
        char* dA = Xs + gra * ROWB + 16 + 32 * gd;
        *(int4*)dA = int4{pack2(a0.x, a0.y), pack2(a0.z, a0.w),
                          pack2(a1.x, a1.y), pack2(a1.z, a1.w)};
        *(int4*)(dA + 16) = int4{pack2(a2.x, a2.y), pack2(a2.z, a2.w),
                                 pack2(a3.x, a3.y), pack2(a3.z, a3.w)};
        char* dB = Xs + grb * ROWB + 16 + 32 * gd;
        *(int4*)dB = int4{pack2(b0.x, b0.y), pack2(b0.z, b0.w),
                          pack2(b1.x, b1.y), pack2(b1.z, b1.w)};
        *(int4*)(dB + 16) = int4{pack2(b2.x, b2.y), pack2(b2.z, b2.w),
                                 pack2(b3.x, b3.y), pack2(b3.z, b3.w)};
    }
    __syncthreads();

    const int lane = t & 63;
    const int w    = t >> 6;     // wave id = N-tile owner
    const int lr   = lane & 15;
    const int lg   = lane >> 4;

    // ---------------- GEMM1: X[64x160] @ Wpre'[160x64] -> pre -> A2s cols 0..63
    {
        f32x4 acc1[4];
#pragma unroll
        for (int m = 0; m < 4; ++m) acc1[m] = (f32x4){0.f, 0.f, 0.f, 0.f};
#pragma unroll
        for (int s = 0; s < 5; ++s) {
            bf16x8 b = *(const bf16x8*)(wpre_p + ((s * 64 + w * 16 + lr) * 32 + lg * 8));
#pragma unroll
            for (int m = 0; m < 4; ++m) {
                bf16x8 a = *(const bf16x8*)(Xs + (m * 16 + lr) * ROWB + s * 64 + lg * 16);
                acc1[m] = __builtin_amdgcn_mfma_f32_16x16x32_bf16(a, b, acc1[m], 0, 0, 0);
            }
        }
        float bp = b_pre[w * 16 + lr];
        int colb = (w * 16 + lr) * 2;
#pragma unroll
        for (int m = 0; m < 4; ++m)
#pragma unroll
            for (int rr = 0; rr < 4; ++rr) {
                int row = m * 16 + lg * 4 + rr;
                float pv = fast_tanh(acc1[m][rr] + bp);
                *(unsigned short*)((char*)A2s + row * 256 + (colb ^ ((row & 7) << 4))) =
                    f2bf(pv);
            }
    }
    __syncthreads();   // pre/h visible (also: all GEMM1 X-reads retired)

    // ---------------- GEMM2: [pre||h][64x128] @ W2'[128x256] + LSTM ----------------
    {
        const int hid = w * 16 + lr;
        // prefetch c_old early (hide latency under MFMAs)
        float cpf[16];
#pragma unroll
        for (int m = 0; m < 4; ++m)
#pragma unroll
            for (int rr = 0; rr < 4; ++rr)
                cpf[m * 4 + rr] =
                    lstm_c[(size_t)(p0 + m * 16 + lg * 4 + rr) * 64 + hid];

        f32x4 acc2[4][4];  // [m][j], gate tile n = w + 4*j  (j: 0=i,1=f,2=g,3=o)
#pragma unroll
        for (int m = 0; m < 4; ++m)
#pragma unroll
            for (int j = 0; j < 4; ++j) acc2[m][j] = (f32x4){0.f, 0.f, 0.f, 0.f};
#pragma unroll
        for (int s = 0; s < 4; ++s) {
            bf16x8 a[4];
#pragma unroll
            for (int m = 0; m < 4; ++m) {
                int row = m * 16 + lr;
                int cb  = (s * 32 + lg * 8) * 2;
                a[m] = *(const bf16x8*)((char*)A2s + row * 256 + (cb ^ ((row & 7) << 4)));
            }
#pragma unroll
            for (int j = 0; j < 4; ++j) {
                int n = w + 4 * j;
                bf16x8 b = *(const bf16x8*)(w2_p + ((s * 256 + n * 16 + lr) * 32 + lg * 8));
#pragma unroll
                for (int m = 0; m < 4; ++m)
                    acc2[m][j] =
                        __builtin_amdgcn_mfma_f32_16x16x32_bf16(a[m], b, acc2[m][j], 0, 0, 0);
            }
        }
        // LSTM pointwise: results -> LDS only (coop full-line stores after sync)
        float bi  = b_lstm[hid],       bfv = b_lstm[64 + hid];
        float bg  = b_lstm[128 + hid], bo  = b_lstm[192 + hid];
#pragma unroll
        for (int m = 0; m < 4; ++m)
#pragma unroll
            for (int rr = 0; rr < 4; ++rr) {
                int row = m * 16 + lg * 4 + rr;
                float iv = fast_sigmoid(acc2[m][0][rr] + bi);
                float fv = fast_sigmoid(acc2[m][1][rr] + bfv);
                float gv = fast_tanh(acc2[m][2][rr] + bg);
                float ov = fast_sigmoid(acc2[m][3][rr] + bo);
                float cn = fv * cpf[m * 4 + rr] + iv * gv;
                float hn = ov * fast_tanh(cn);
                int sw = (row & 7) << 4;
                char* rp = Xs + row * ROWB;       // Xs dead since GEMM1
                *(unsigned short*)(rp + ((2 * hid) ^ sw))       = f2bf(hn);
                *(unsigned short*)(rp + 128 + ((2 * hid) ^ sw)) = f2bf(cn);
            }
    }
    __syncthreads();   // hn/cn visible

    // ---------------- cooperative full-line c/h stores (non-temporal) --------------
    {
#pragma unroll
        for (int q = 0; q < 2; ++q) {
            int row = (t >> 3) + q * 32;
            int ch  = t & 7;
            const char* rp = Xs + row * ROWB;
            int off = (ch * 16) ^ ((row & 7) << 4);
            int4 hv = *(const int4*)(rp + off);
            int4 cv = *(const int4*)(rp + 128 + off);
            size_t rb = (size_t)(p0 + row) * 64 + ch * 8;
            f32x4 a0{bf2f_lo(cv.x), bf2f_hi(cv.x), bf2f_lo(cv.y), bf2f_hi(cv.y)};
            f32x4 a1{bf2f_lo(cv.z), bf2f_hi(cv.z), bf2f_lo(cv.w), bf2f_hi(cv.w)};
            __builtin_nontemporal_store(a0, (f32x4*)(out + OUT_C + rb));
            __builtin_nontemporal_store(a1, (f32x4*)(out + OUT_C + rb + 4));
            f32x4 b0{bf2f_lo(hv.x), bf2f_hi(hv.x), bf2f_lo(hv.y), bf2f_hi(hv.y)};
            f32x4 b1{bf2f_lo(hv.z), bf2f_hi(hv.z), bf2f_lo(hv.w), bf2f_hi(hv.w)};
            __builtin_nontemporal_store(b0, (f32x4*)(out + OUT_H + rb));
            __builtin_nontemporal_store(b1, (f32x4*)(out + OUT_H + rb + 4));
        }
    }

    // ---------------- GEMM3: hn[64x64] @ Wpost2'[64x160], tanh -> dyn/lat ----------
    // wave w owns tiles {2w+2, 2w+3} = lat 32-col line w of every row (single-writer
    // full lines); wave 0 additionally does the dyn tile (n'=0).
    {
        f32x4 acc3[4][3];
#pragma unroll
        for (int m = 0; m < 4; ++m)
#pragma unroll
            for (int jj = 0; jj < 3; ++jj) acc3[m][jj] = (f32x4){0.f, 0.f, 0.f, 0.f};
#pragma unroll
        for (int s = 0; s < 2; ++s) {
            bf16x8 a[4];
#pragma unroll
            for (int m = 0; m < 4; ++m) {
                int row = m * 16 + lr;
                a[m] = *(const bf16x8*)(Xs + row * ROWB +
                                        ((s * 64 + lg * 16) ^ ((lr & 7) << 4)));
            }
#pragma unroll
            for (int jj = 0; jj < 3; ++jj) {
                if (jj == 0 && w != 0) continue;
                int n = (jj == 0) ? 0 : (2 * w + 1 + jj);
                bf16x8 b =
                    *(const bf16x8*)(wpost_p + ((s * 160 + n * 16 + lr) * 32 + lg * 8));
#pragma unroll
                for (int m = 0; m < 4; ++m)
                    acc3[m][jj] = __builtin_amdgcn_mfma_f32_16x16x32_bf16(a[m], b,
                                                                          acc3[m][jj],
                                                                          0, 0, 0);
            }
        }
        // epilogue: per-lane scalar stores, every 128B line single-writer
        if (w == 0 && lr < 8) {                       // dyn tile
            float bpv = b_post[lr];
#pragma unroll
            for (int m = 0; m < 4; ++m)
#pragma unroll
                for (int rr = 0; rr < 4; ++rr) {
                    int row = m * 16 + lg * 4 + rr;
                    out[(size_t)(p0 + row) * 8 + lr] =
                        fast_tanh(acc3[m][0][rr] + bpv);
                }
        }
#pragma unroll
        for (int jj = 1; jj < 3; ++jj) {              // lat tiles (line w)
            int n = 2 * w + 1 + jj;
            int L = n * 16 + lr - 32;                 // lat col 0..127
            float bpv = b_post[L + 8];
#pragma unroll
            for (int m = 0; m < 4; ++m)
#pragma unroll
                for (int rr = 0; rr < 4; ++rr) {
                    int row = m * 16 + lg * 4 + rr;
                    out[OUT_LAT + (size_t)(p0 + row) * 128 + L] =
                        fast_tanh(acc3[m][jj][rr] + bpv);
                }
        }
    }
}

extern "C" void kernel_launch(void* const* d_in, const int* in_sizes, int n_in,
                              void* d_out, int out_size, void* d_ws, size_t ws_size,
                              hipStream_t stream) {
    const float* dyn_in   = (const float*)d_in[0];
    const float* lat_prev = (const float*)d_in[1];
    const float* lstm_c   = (const float*)d_in[2];
    const float* lstm_h   = (const float*)d_in[3];
    const float* W_pre  = (const float*)d_in[7];
    const float* b_pre  = (const float*)d_in[8];
    const float* W_ih   = (const float*)d_in[9];
    const float* W_hh   = (const float*)d_in[10];
    const float* b_lstm = (const float*)d_in[11];
    const float* W_post = (const float*)d_in[12];
    const float* b_post = (const float*)d_in[13];
    unsigned short* wsp = (unsigned short*)d_ws;

    prep_weights<<<(WTOTAL + 255) / 256, 256, 0, stream>>>(W_pre, W_ih, W_hh, W_post, wsp);
    knet_fused<<<NCELL / 64, 256, 0, stream>>>(dyn_in, lat_prev, lstm_c, lstm_h,
                                               wsp, b_pre, b_lstm, b_post, (float*)d_out);
}

// Round 15
// 185.570 us; speedup vs baseline: 1.5495x; 1.0062x over previous
//
#include <hip/hip_runtime.h>
#include <stdint.h>

#define NCELL (512 * 512)
#define DIN   136

// output layout (flat f32, concat in return order)
#define OUT_LAT 2097152ull                 // N*8
#define OUT_C   35651584ull                // OUT_LAT + N*128
#define OUT_H   52428800ull                // OUT_C + N*64

// packed-weight offsets in d_ws (bf16 elements)
#define WPRE_OFF  0        // [5][64][32]   = 10240
#define W2_OFF    10240    // [4][256][32]  = 32768
#define WPOST_OFF 43008    // [2][160][32]  = 10240 ; n' 0..7 dyn, 8..31 pad, 32..159 lat
#define WTOTAL    53248

#define ROWB 336           // Xs bytes per cell-row

typedef __bf16 bf16x8 __attribute__((ext_vector_type(8)));
typedef __bf16 bf16x2 __attribute__((ext_vector_type(2)));
typedef float  f32x4  __attribute__((ext_vector_type(4)));

// Native casts -> compiler emits v_cvt_pk_bf16_f32 (RTNE)
__device__ __forceinline__ unsigned short f2bf(float f) {
    __bf16 v = (__bf16)f;
    unsigned short r;
    __builtin_memcpy(&r, &v, 2);
    return r;
}
__device__ __forceinline__ int pack2(float a, float b) {
    bf16x2 v{(__bf16)a, (__bf16)b};
    int r;
    __builtin_memcpy(&r, &v, 4);
    return r;
}
__device__ __forceinline__ float fast_sigmoid(float x) {
    return __builtin_amdgcn_rcpf(1.f + __expf(-x));
}
__device__ __forceinline__ float fast_tanh(float x) {
    float e = __expf(2.f * x);              // inf-safe: rcp(inf)=0 -> 1; e->0 -> -1
    return 1.f - 2.f * __builtin_amdgcn_rcpf(e + 1.f);
}
__device__ __forceinline__ float bf2f_lo(int u) {
    return __uint_as_float((unsigned)u << 16);
}
__device__ __forceinline__ float bf2f_hi(int u) {
    return __uint_as_float((unsigned)u & 0xffff0000u);
}

// Repack weights to bf16, MFMA-B-fragment-friendly: [K/32][Ncol][32]
__global__ void prep_weights(const float* __restrict__ Wpre,
                             const float* __restrict__ Wih,
                             const float* __restrict__ Whh,
                             const float* __restrict__ Wpost,
                             unsigned short* __restrict__ ws) {
    int i = blockIdx.x * 256 + threadIdx.x;
    if (i < 10240) {                                   // Wpre' : K 136->160 pad, N=64
        int k = i & 31, n = (i >> 5) & 63, s = i >> 11;
        int K = s * 32 + k;
        ws[i] = (K < DIN) ? f2bf(Wpre[K * 64 + n]) : (unsigned short)0;
    } else if (i < 43008) {                            // W2'   : K=128 (ih||hh), N=256
        int j = i - 10240;
        int k = j & 31, n = (j >> 5) & 255, s = j >> 13;
        int K = s * 32 + k;
        float v = (K < 64) ? Wih[K * 256 + n] : Whh[(K - 64) * 256 + n];
        ws[i] = f2bf(v);
    } else if (i < WTOTAL) {                           // Wpost2: [2][160][32], line-aligned
        int j = i - 43008;
        int k = j & 31;
        int t2 = j >> 5;            // 0..319
        int n = t2 % 160;
        int s = t2 / 160;
        int K = s * 32 + k;         // 0..63
        float v = 0.f;
        if (n < 8)        v = Wpost[K * DIN + n];          // dyn cols
        else if (n >= 32) v = Wpost[K * DIN + (n - 24)];   // lat cols 0..127
        ws[i] = f2bf(v);
    }
}

// Cooperative fused kernel: block = 256 threads (4 waves) = 64 cells.
// R7 structure verbatim (proven best: 4096 dispatch-ordered blocks, 4/CU,
// two-buffer race-free layout, coop full-line c/h stores, line-aligned lat
// tiles) with ONE change: analytic gather topology (drops the 8MB coming_from
// stream and the dependent index->lat load chain from phase 0).
__global__ __launch_bounds__(256, 4) void knet_fused(
    const float* __restrict__ dyn_in,
    const float* __restrict__ lat_prev,
    const float* __restrict__ lstm_c,
    const float* __restrict__ lstm_h,
    const unsigned short* __restrict__ wsp,
    const float* __restrict__ b_pre,
    const float* __restrict__ b_lstm,
    const float* __restrict__ b_post,
    float* __restrict__ out) {
    // Xs: X bf16 cols 0..159 during GEMM1 (bytes 272..319 zero pad).
    //     During LSTM epilogue (Xs dead): hn -> bytes 0..127 (XOR swz),
    //     cn -> bytes 128..255 (same swz). Read by GEMM3 + coop stores.
    __shared__ __align__(16) char Xs[64 * ROWB];
    // A2s: [64][128] bf16 (cols 0-63 = pre, 64-127 = h_prev), XOR-swizzled rows
    __shared__ __align__(16) unsigned short A2s[64 * 128];

    const int t  = threadIdx.x;
    const int p0 = blockIdx.x * 64;
    const unsigned short* wpre_p  = wsp + WPRE_OFF;
    const unsigned short* w2_p    = wsp + W2_OFF;
    const unsigned short* wpost_p = wsp + WPOST_OFF;

    // ---------------- phase 0: staging ----------------
    {
        // h_prev -> A2s cols 64..127 (bf16, swizzled). 16 values/thread.
        int r = t >> 2, q = t & 3;
        int sw = (r & 7) << 4;
        const float4* hp = (const float4*)(lstm_h + (size_t)(p0 + r) * 64 + q * 16);
        float4 v0 = hp[0], v1 = hp[1], v2 = hp[2], v3 = hp[3];
        char* rowp = (char*)A2s + r * 256;
        int4 w0{pack2(v0.x, v0.y), pack2(v0.z, v0.w), pack2(v1.x, v1.y), pack2(v1.z, v1.w)};
        int4 w1{pack2(v2.x, v2.y), pack2(v2.z, v2.w), pack2(v3.x, v3.y), pack2(v3.z, v3.w)};
        *(int4*)(rowp + ((128 + 32 * q) ^ sw))      = w0;
        *(int4*)(rowp + ((128 + 32 * q + 16) ^ sw)) = w1;

        // zero pad X cols 136..159 (bytes 272..319)
        if (q < 3) *(int4*)(Xs + r * ROWB + 272 + 16 * q) = int4{0, 0, 0, 0};
    }
    if (t < 128) {  // dyn_in -> X cols 0..7
        int r = t >> 1, c = (t & 1) * 4;
        float4 v = *(const float4*)(dyn_in + (size_t)(p0 + r) * 8 + c);
        int2 wv{pack2(v.x, v.y), pack2(v.z, v.w)};
        *(int2*)(Xs + r * ROWB + c * 2) = wv;
    }
    {   // lat gather -> X cols 8..135 ; analytic topology (= _build_topology)
        const int gra = t >> 3, grb = gra + 32, gd = t & 7;
        // offsets {(-1,-1),(-1,0),(-1,1),(0,-1),(0,1),(1,-1),(1,0),(1,1)}
        const int dr = (gd < 3) ? -1 : ((gd < 5) ? 0 : 1);
        const int dc = (gd < 3) ? (gd - 1)
                                : ((gd < 5) ? ((gd == 3) ? -1 : 1) : (gd - 6));
        const int nr = (p0 >> 9) + dr;        // all 64 cells share one grid row
        const int colbase = p0 & 511;
        int nc_a = colbase + gra + dc;
        int nc_b = colbase + grb + dc;
        int src_a, src_b;
        if (nr == -1) {
            src_a = (nc_a + 256) & 511;
            src_b = (nc_b + 256) & 511;
        } else if (nr == 512) {
            src_a = (511 << 9) | ((nc_a + 256) & 511);
            src_b = (511 << 9) | ((nc_b + 256) & 511);
        } else {
            src_a = (nr << 9) | ((nc_a + 512) & 511);
            src_b = (nr << 9) | ((nc_b + 512) & 511);
        }
        const float4* lpA = (const float4*)(lat_prev + (size_t)src_a * 128 + gd * 16);
        float4 a0 = lpA[0], a1 = lpA[1], a2 = lpA[2], a3 = lpA[3];
        const float4* lpB = (const float4*)(lat_prev + (size_t)src_b * 128 + gd * 16);
        float4 b0 = lpB[0], b1 = lpB[1], b2 = lpB[2], b3 = lpB[3];
        char* dA = Xs + gra * ROWB + 16 + 32 * gd;
        *(int4*)dA = int4{pack2(a0.x, a0.y), pack2(a0.z, a0.w),
                          pack2(a1.x, a1.y), pack2(a1.z, a1.w)};
        *(int4*)(dA + 16) = int4{pack2(a2.x, a2.y), pack2(a2.z, a2.w),
                                 pack2(a3.x, a3.y), pack2(a3.z, a3.w)};
        char* dB = Xs + grb * ROWB + 16 + 32 * gd;
        *(int4*)dB = int4{pack2(b0.x, b0.y), pack2(b0.z, b0.w),
                          pack2(b1.x, b1.y), pack2(b1.z, b1.w)};
        *(int4*)(dB + 16) = int4{pack2(b2.x, b2.y), pack2(b2.z, b2.w),
                                 pack2(b3.x, b3.y), pack2(b3.z, b3.w)};
    }
    __syncthreads();

    const int lane = t & 63;
    const int w    = t >> 6;     // wave id = N-tile owner
    const int lr   = lane & 15;
    const int lg   = lane >> 4;

    // ---------------- GEMM1: X[64x160] @ Wpre'[160x64] -> pre -> A2s cols 0..63
    {
        f32x4 acc1[4];
#pragma unroll
        for (int m = 0; m < 4; ++m) acc1[m] = (f32x4){0.f, 0.f, 0.f, 0.f};
#pragma unroll
        for (int s = 0; s < 5; ++s) {
            bf16x8 b = *(const bf16x8*)(wpre_p + ((s * 64 + w * 16 + lr) * 32 + lg * 8));
#pragma unroll
            for (int m = 0; m < 4; ++m) {
                bf16x8 a = *(const bf16x8*)(Xs + (m * 16 + lr) * ROWB + s * 64 + lg * 16);
                acc1[m] = __builtin_amdgcn_mfma_f32_16x16x32_bf16(a, b, acc1[m], 0, 0, 0);
            }
        }
        float bp = b_pre[w * 16 + lr];
        int colb = (w * 16 + lr) * 2;
#pragma unroll
        for (int m = 0; m < 4; ++m)
#pragma unroll
            for (int rr = 0; rr < 4; ++rr) {
                int row = m * 16 + lg * 4 + rr;
                float pv = fast_tanh(acc1[m][rr] + bp);
                *(unsigned short*)((char*)A2s + row * 256 + (colb ^ ((row & 7) << 4))) =
                    f2bf(pv);
            }
    }
    __syncthreads();   // pre/h visible (also: all GEMM1 X-reads retired)

    // ---------------- GEMM2: [pre||h][64x128] @ W2'[128x256] + LSTM ----------------
    {
        const int hid = w * 16 + lr;
        // prefetch c_old early (hide latency under MFMAs)
        float cpf[16];
#pragma unroll
        for (int m = 0; m < 4; ++m)
#pragma unroll
            for (int rr = 0; rr < 4; ++rr)
                cpf[m * 4 + rr] =
                    lstm_c[(size_t)(p0 + m * 16 + lg * 4 + rr) * 64 + hid];

        f32x4 acc2[4][4];  // [m][j], gate tile n = w + 4*j  (j: 0=i,1=f,2=g,3=o)
#pragma unroll
        for (int m = 0; m < 4; ++m)
#pragma unroll
            for (int j = 0; j < 4; ++j) acc2[m][j] = (f32x4){0.f, 0.f, 0.f, 0.f};
#pragma unroll
        for (int s = 0; s < 4; ++s) {
            bf16x8 a[4];
#pragma unroll
            for (int m = 0; m < 4; ++m) {
                int row = m * 16 + lr;
                int cb  = (s * 32 + lg * 8) * 2;
                a[m] = *(const bf16x8*)((char*)A2s + row * 256 + (cb ^ ((row & 7) << 4)));
            }
#pragma unroll
            for (int j = 0; j < 4; ++j) {
                int n = w + 4 * j;
                bf16x8 b = *(const bf16x8*)(w2_p + ((s * 256 + n * 16 + lr) * 32 + lg * 8));
#pragma unroll
                for (int m = 0; m < 4; ++m)
                    acc2[m][j] =
                        __builtin_amdgcn_mfma_f32_16x16x32_bf16(a[m], b, acc2[m][j], 0, 0, 0);
            }
        }
        // LSTM pointwise: results -> LDS only (coop full-line stores after sync)
        float bi  = b_lstm[hid],       bfv = b_lstm[64 + hid];
        float bg  = b_lstm[128 + hid], bo  = b_lstm[192 + hid];
#pragma unroll
        for (int m = 0; m < 4; ++m)
#pragma unroll
            for (int rr = 0; rr < 4; ++rr) {
                int row = m * 16 + lg * 4 + rr;
                float iv = fast_sigmoid(acc2[m][0][rr] + bi);
                float fv = fast_sigmoid(acc2[m][1][rr] + bfv);
                float gv = fast_tanh(acc2[m][2][rr] + bg);
                float ov = fast_sigmoid(acc2[m][3][rr] + bo);
                float cn = fv * cpf[m * 4 + rr] + iv * gv;
                float hn = ov * fast_tanh(cn);
                int sw = (row & 7) << 4;
                char* rp = Xs + row * ROWB;       // Xs dead since GEMM1
                *(unsigned short*)(rp + ((2 * hid) ^ sw))       = f2bf(hn);
                *(unsigned short*)(rp + 128 + ((2 * hid) ^ sw)) = f2bf(cn);
            }
    }
    __syncthreads();   // hn/cn visible

    // ---------------- cooperative full-line c/h stores ----------------
    {
#pragma unroll
        for (int q = 0; q < 2; ++q) {
            int row = (t >> 3) + q * 32;
            int ch  = t & 7;
            const char* rp = Xs + row * ROWB;
            int off = (ch * 16) ^ ((row & 7) << 4);
            int4 hv = *(const int4*)(rp + off);
            int4 cv = *(const int4*)(rp + 128 + off);
            size_t rb = (size_t)(p0 + row) * 64 + ch * 8;
            float4 a0{bf2f_lo(cv.x), bf2f_hi(cv.x), bf2f_lo(cv.y), bf2f_hi(cv.y)};
            float4 a1{bf2f_lo(cv.z), bf2f_hi(cv.z), bf2f_lo(cv.w), bf2f_hi(cv.w)};
            *(float4*)(out + OUT_C + rb)     = a0;
            *(float4*)(out + OUT_C + rb + 4) = a1;
            float4 b0{bf2f_lo(hv.x), bf2f_hi(hv.x), bf2f_lo(hv.y), bf2f_hi(hv.y)};
            float4 b1{bf2f_lo(hv.z), bf2f_hi(hv.z), bf2f_lo(hv.w), bf2f_hi(hv.w)};
            *(float4*)(out + OUT_H + rb)     = b0;
            *(float4*)(out + OUT_H + rb + 4) = b1;
        }
    }

    // ---------------- GEMM3: hn[64x64] @ Wpost2'[64x160], tanh -> dyn/lat ----------
    // wave w owns tiles {2w+2, 2w+3} = lat 32-col line w of every row (single-writer
    // full lines); wave 0 additionally does the dyn tile (n'=0).
    {
        f32x4 acc3[4][3];
#pragma unroll
        for (int m = 0; m < 4; ++m)
#pragma unroll
            for (int jj = 0; jj < 3; ++jj) acc3[m][jj] = (f32x4){0.f, 0.f, 0.f, 0.f};
#pragma unroll
        for (int s = 0; s < 2; ++s) {
            bf16x8 a[4];
#pragma unroll
            for (int m = 0; m < 4; ++m) {
                int row = m * 16 + lr;
                a[m] = *(const bf16x8*)(Xs + row * ROWB +
                                        ((s * 64 + lg * 16) ^ ((lr & 7) << 4)));
            }
#pragma unroll
            for (int jj = 0; jj < 3; ++jj) {
                if (jj == 0 && w != 0) continue;
                int n = (jj == 0) ? 0 : (2 * w + 1 + jj);
                bf16x8 b =
                    *(const bf16x8*)(wpost_p + ((s * 160 + n * 16 + lr) * 32 + lg * 8));
#pragma unroll
                for (int m = 0; m < 4; ++m)
                    acc3[m][jj] = __builtin_amdgcn_mfma_f32_16x16x32_bf16(a[m], b,
                                                                          acc3[m][jj],
                                                                          0, 0, 0);
            }
        }
        // epilogue: per-lane scalar stores, every 128B line single-writer
        if (w == 0 && lr < 8) {                       // dyn tile
            float bpv = b_post[lr];
#pragma unroll
            for (int m = 0; m < 4; ++m)
#pragma unroll
                for (int rr = 0; rr < 4; ++rr) {
                    int row = m * 16 + lg * 4 + rr;
                    out[(size_t)(p0 + row) * 8 + lr] =
                        fast_tanh(acc3[m][0][rr] + bpv);
                }
        }
#pragma unroll
        for (int jj = 1; jj < 3; ++jj) {              // lat tiles (line w)
            int n = 2 * w + 1 + jj;
            int L = n * 16 + lr - 32;                 // lat col 0..127
            float bpv = b_post[L + 8];
#pragma unroll
            for (int m = 0; m < 4; ++m)
#pragma unroll
                for (int rr = 0; rr < 4; ++rr) {
                    int row = m * 16 + lg * 4 + rr;
                    out[OUT_LAT + (size_t)(p0 + row) * 128 + L] =
                        fast_tanh(acc3[m][jj][rr] + bpv);
                }
        }
    }
}

extern "C" void kernel_launch(void* const* d_in, const int* in_sizes, int n_in,
                              void* d_out, int out_size, void* d_ws, size_t ws_size,
                              hipStream_t stream) {
    const float* dyn_in   = (const float*)d_in[0];
    const float* lat_prev = (const float*)d_in[1];
    const float* lstm_c   = (const float*)d_in[2];
    const float* lstm_h   = (const float*)d_in[3];
    const float* W_pre  = (const float*)d_in[7];
    const float* b_pre  = (const float*)d_in[8];
    const float* W_ih   = (const float*)d_in[9];
    const float* W_hh   = (const float*)d_in[10];
    const float* b_lstm = (const float*)d_in[11];
    const float* W_post = (const float*)d_in[12];
    const float* b_post = (const float*)d_in[13];
    unsigned short* wsp = (unsigned short*)d_ws;

    prep_weights<<<(WTOTAL + 255) / 256, 256, 0, stream>>>(W_pre, W_ih, W_hh, W_post, wsp);
    knet_fused<<<NCELL / 64, 256, 0, stream>>>(dyn_in, lat_prev, lstm_c, lstm_h,
                                               wsp, b_pre, b_lstm, b_post, (float*)d_out);
}